// Round 2
// baseline (371.014 us; speedup 1.0000x reference)
//
#include <hip/hip_runtime.h>
#include <stdint.h>

// DilateAttention: B=16, C=384 (12 heads x 32), H=W=56, 3x3 window, dil=2,
// reflect pad. Memory-bound; ideal HBM ~308 MB (~45-49 us at 6.3 TB/s).
//
// R5: T14 register staging. R4 post-mortem: counted-vmcnt ledger over
// global_load_lds was time-identical to R3's __syncthreads drain -> the
// compiler re-serialized anyway (it cannot disambiguate in-flight LDS-DMA
// destinations from ds_read addresses, so it drains vmcnt before the LDS
// reads). Fix: stage global->VGPR->ds_write (no LDS-DMA at all). ds_read
// then carries no VMEM hazard; the only vmcnt wait is on staged registers
// issued one full step earlier (issue-early / write-late, T14).
// Uniform step t = 0..7 (4 score steps over k, 4 output steps over v):
//   top:    issue chunk t+2 -> regs S[t&1]   (3x dwordx4 per lane)
//           (pass1 only) q(t+1) prefetch
//   mid:    compute on lds buf[t&1]          (ds_read + FMA, no vmem waits)
//   BAR
//   bottom: ds_write chunk t+1 from S[(t+1)&1] -> buf[(t+1)&1]
//           s_waitcnt lgkmcnt(0); BAR        (publish)
// Reg sets alternate: S[x] is issued at step top, consumed (written to LDS)
// at the END of the NEXT step -> one full step of flight per staged chunk.
// blocks = 16*12*7 = 1344, 512 thr, LDS 43008 B -> 3 blk/CU, 24 waves/CU.

#define BB 16
#define CH 384
#define HH 56
#define WW 56
#define NH 12
#define DD 32
#define HW (HH * WW)
#define KSQ 9
#define SCALE 0.17677669529663687f  // 32^-0.5

#define BAND 8                 // pixel rows per block
#define DCH 8                  // d-channels per staged chunk
#define NCHUNK (DD / DCH)      // 4
#define MAXROWS 12             // band + 2*halo
#define SLICE (MAXROWS * WW)   // floats per d-slice in LDS (672)
#define LBUF (DCH * SLICE)     // floats per buffer (5376)

#define FENCE()  asm volatile("" ::: "memory")
#define BAR()    do { FENCE(); __builtin_amdgcn_s_barrier(); FENCE(); } while (0)
#define LGKM0()  asm volatile("s_waitcnt lgkmcnt(0)" ::: "memory")

// Load one d-slice (rows lo..hi of plane wv of the chunk) into 3 float4s.
// Covers Sbytes (2240 or 2688) with 1KB wave-chunks at offsets 0, 1024,
// Sbytes-1024 (third overlaps second; duplicate data, writes are idempotent).
// All offsets 16B-aligned: planebase*4 and lo*224 are multiples of 16,
// Sbytes = nr*224 is a multiple of 16.
__device__ __forceinline__ void ldg3(const float* __restrict__ plane0,
                                     int Sbytes, int wv, int lane, float4* r) {
    const char* g = (const char*)(plane0 + wv * HW) + lane * 16;
    r[0] = *(const float4*)(g);
    r[1] = *(const float4*)(g + 1024);
    r[2] = *(const float4*)(g + (Sbytes - 1024));
}

__device__ __forceinline__ void dsw3(float* ldsbuf, int Sbytes, int wv,
                                     int lane, const float4* r) {
    char* l = (char*)(ldsbuf + wv * SLICE) + lane * 16;
    *(float4*)(l) = r[0];
    *(float4*)(l + 1024) = r[1];
    *(float4*)(l + (Sbytes - 1024)) = r[2];
}

__global__ __launch_bounds__(512, 6)
void dilate_attn_kernel(const float* __restrict__ q,
                        const float* __restrict__ k,
                        const float* __restrict__ v,
                        float* __restrict__ out) {
    __shared__ __align__(16) float lds[2][LBUF];  // 43008 B

    const int band = blockIdx.x;       // 0..6
    const int n    = blockIdx.y;       // head
    const int b    = blockIdx.z;

    const int tid  = threadIdx.x;      // 0..511
    const int lane = tid & 63;
    const int wv   = tid >> 6;         // 0..7: band row AND staging slice

    const bool act = lane < WW;        // lanes 56..63 idle in compute/store
    const int w  = act ? lane : (WW - 1);
    const int h0 = band * BAND;
    const int h  = h0 + wv;

    // staged (clamped, contiguous) row range
    const int lo = (h0 - 2 < 0) ? 0 : h0 - 2;
    const int hi = (h0 + 9 > HH - 1) ? HH - 1 : h0 + 9;
    const int Sbytes = (hi - lo + 1) * WW * 4;   // 2240 or 2688

    // 9 window offsets inside an LDS d-slice (reflected rows/cols)
    int off9[KSQ];
    {
        int wc[3];
#pragma unroll
        for (int j = 0; j < 3; ++j) {
            int c = w + 2 * (j - 1);
            c = (c < 0) ? -c : ((c >= WW) ? (2 * WW - 2 - c) : c);
            wc[j] = c;
        }
#pragma unroll
        for (int i = 0; i < 3; ++i) {
            int rr = h + 2 * (i - 1);
            rr = (rr < 0) ? -rr : ((rr >= HH) ? (2 * HH - 2 - rr) : rr);
            rr -= lo;                  // LDS row index, in [0, nr)
#pragma unroll
            for (int j = 0; j < 3; ++j) off9[i * 3 + j] = rr * WW + wc[j];
        }
    }

    const int planebase = (b * CH + n * DD) * HW;     // first d-plane of head
    const float* qp = q + planebase + h * WW + w;
    const float* kstage = k + planebase + lo * WW;
    const float* vstage = v + planebase + lo * WW;

    float sc[KSQ];
#pragma unroll
    for (int ii = 0; ii < KSQ; ++ii) sc[ii] = 0.f;

    float4 S[2][3];                    // two staging reg sets (24 VGPRs)

    // ---- prologue: chunk0 -> S[0] -> buf0; chunk1 -> S[1] (in flight) ----
    ldg3(kstage, Sbytes, wv, lane, S[0]);
    FENCE();
    ldg3(kstage + DCH * HW, Sbytes, wv, lane, S[1]);
    FENCE();
    float qd[DCH];
#pragma unroll
    for (int j = 0; j < DCH; ++j) qd[j] = qp[j * HW];
    FENCE();
    dsw3(lds[0], Sbytes, wv, lane, S[0]);   // compiler waits S[0] only
    LGKM0();
    BAR();                                   // buf0 (chunk0) published

    // ---------------- pass 1: scores over 4 k-chunks ----------------
#pragma unroll
    for (int c = 0; c < NCHUNK; ++c) {
        // top: issue chunk c+2 into S[c&1] (chunks 2,3 = k; 4,5 = v0,v1)
        const float* src = (c + 2 < NCHUNK)
                               ? (kstage + (c + 2) * DCH * HW)
                               : (vstage + (c + 2 - NCHUNK) * DCH * HW);
        ldg3(src, Sbytes, wv, lane, S[c & 1]);
        FENCE();
        float qn[DCH];
        if (c < NCHUNK - 1) {          // q prefetch for c+1
#pragma unroll
            for (int j = 0; j < DCH; ++j) qn[j] = qp[((c + 1) * DCH + j) * HW];
        }
        // mid: compute on buf[c&1] (wait here is q(c), issued one step ago)
        const float* Bf = lds[c & 1];
#pragma unroll
        for (int j = 0; j < DCH; ++j) {
            const float* Ls = Bf + j * SLICE;
            const float qj = qd[j];
#pragma unroll
            for (int ii = 0; ii < KSQ; ++ii)
                sc[ii] = fmaf(qj, Ls[off9[ii]], sc[ii]);
        }
        if (c < NCHUNK - 1) {
#pragma unroll
            for (int j = 0; j < DCH; ++j) qd[j] = qn[j];
        }
        BAR();                          // all waves done reading buf[c&1]
        // bottom: write chunk c+1 from S[(c+1)&1] into buf[(c+1)&1]
        dsw3(lds[(c + 1) & 1], Sbytes, wv, lane, S[(c + 1) & 1]);
        LGKM0();
        BAR();                          // publish chunk c+1
    }

    // ---------------- softmax over the 9 positions ----------------
    {
        float m = sc[0];
#pragma unroll
        for (int ii = 1; ii < KSQ; ++ii) m = fmaxf(m, sc[ii]);
        float sum = 0.f;
#pragma unroll
        for (int ii = 0; ii < KSQ; ++ii) {
            sc[ii] = __expf((sc[ii] - m) * SCALE);
            sum += sc[ii];
        }
        const float inv = 1.f / sum;
#pragma unroll
        for (int ii = 0; ii < KSQ; ++ii) sc[ii] *= inv;
    }

    // ---------------- pass 2: output over 4 v-chunks ----------------
    // entering: buf[0] = chunk4 (v0) published; S[1] = chunk5 (v1) in flight
    float* op = out + ((b * HH + h) * WW + w) * CH + n * DD;

#pragma unroll
    for (int p = 0; p < NCHUNK; ++p) {   // global step t = 4 + p; t&1 == p&1
        // top: issue chunk t+2 (= v(p+2)) into S[p&1]
        if (p + 2 < NCHUNK) {
            ldg3(vstage + (p + 2) * DCH * HW, Sbytes, wv, lane, S[p & 1]);
            FENCE();
        }
        // mid: compute on buf[p&1]
        const float* Bf = lds[p & 1];
        float o[DCH];
#pragma unroll
        for (int j = 0; j < DCH; ++j) {
            const float* Ls = Bf + j * SLICE;
            float acc = 0.f;
#pragma unroll
            for (int ii = 0; ii < KSQ; ++ii)
                acc = fmaf(sc[ii], Ls[off9[ii]], acc);
            o[j] = acc;
        }
        if (act) {
            *(float4*)(op + p * DCH)     = make_float4(o[0], o[1], o[2], o[3]);
            *(float4*)(op + p * DCH + 4) = make_float4(o[4], o[5], o[6], o[7]);
        }
        if (p < NCHUNK - 1) {
            BAR();                      // all waves done reading buf[p&1]
            // bottom: write chunk t+1 (= v(p+1)) from S[(p+1)&1]
            dsw3(lds[(p + 1) & 1], Sbytes, wv, lane, S[(p + 1) & 1]);
            LGKM0();
            BAR();                      // publish
        }
    }
}

extern "C" void kernel_launch(void* const* d_in, const int* in_sizes, int n_in,
                              void* d_out, int out_size, void* d_ws, size_t ws_size,
                              hipStream_t stream) {
    const float* q = (const float*)d_in[0];
    const float* k = (const float*)d_in[1];
    const float* v = (const float*)d_in[2];
    float* out = (float*)d_out;

    dim3 grid(HH / BAND, NH, BB);   // 7 x 12 x 16 = 1344 blocks
    dilate_attn_kernel<<<grid, 512, 0, stream>>>(q, k, v, out);
}

// Round 5
// 300.351 us; speedup vs baseline: 1.2353x; 1.2353x over previous
//
#include <hip/hip_runtime.h>
#include <stdint.h>

// DilateAttention: B=16, C=384 (12 heads x 32), H=W=56, 3x3 window, dil=2,
// reflect pad. Memory-bound; ideal HBM ~308 MB (~45-49 us at 6.3 TB/s).
//
// R6 (3rd submit; rounds 3-4 were infra failures, kernel audited clean:
// uniform barriers, in-bounds, 16B-aligned -- see journal):
// R5's T14 register staging, with the staging actually IN registers.
// R5 post-mortem: S[2][3] indexed by (c&1) -> runtime index at SROA time
// (rule #20) -> scratch alloc -> +440 MB phantom HBM traffic (FETCH 347 MB,
// WRITE 366 MB, VGPR stuck at 40). The pipeline itself sustained 3.2 TB/s
// even at 2.6x bytes, so the overlap structure is kept and the 8 chunk
// steps are HAND-unrolled with two NAMED float4 triples (A0..A2 / B0..B2)
// alternating by textual position -- every staging access is static.
// Step t: {issue chunk t+2 -> free triple} {compute buf[t&1]} BAR
//         {ds_write chunk t+1 from other triple -> buf[(t+1)&1]} lgkm0 BAR.
// blocks = 16*12*7 = 1344, 512 thr, LDS 43008 B -> 3 blk/CU, 24 waves/CU.

#define BB 16
#define CH 384
#define HH 56
#define WW 56
#define NH 12
#define DD 32
#define HW (HH * WW)
#define KSQ 9
#define SCALE 0.17677669529663687f  // 32^-0.5

#define BAND 8                 // pixel rows per block
#define DCH 8                  // d-channels per staged chunk
#define NCHUNK (DD / DCH)      // 4
#define MAXROWS 12             // band + 2*halo
#define SLICE (MAXROWS * WW)   // floats per d-slice in LDS (672)
#define LBUF (DCH * SLICE)     // floats per buffer (5376)

#define FENCE()  asm volatile("" ::: "memory")
#define BAR()    do { FENCE(); __builtin_amdgcn_s_barrier(); FENCE(); } while (0)
#define LGKM0()  asm volatile("s_waitcnt lgkmcnt(0)" ::: "memory")

// Stage one d-slice (rows lo..hi of plane wv) as 3x 1KB wave-chunks at byte
// offsets 0, 1024, Sbytes-1024 (third overlaps second; duplicate data,
// idempotent). All offsets 16B-aligned (planebase*4, lo*224, Sbytes mult 16).
#define LDG3(d0, d1, d2, plane0) do {                                   \
    const char* g_ = (const char*)((plane0) + wv * HW) + lane * 16;     \
    d0 = *(const float4*)(g_);                                          \
    d1 = *(const float4*)(g_ + 1024);                                   \
    d2 = *(const float4*)(g_ + Stail); } while (0)

#define DSW3(buf, s0, s1, s2) do {                                      \
    char* l_ = (char*)((buf) + wv * SLICE) + lane * 16;                 \
    *(float4*)(l_) = s0;                                                \
    *(float4*)(l_ + 1024) = s1;                                         \
    *(float4*)(l_ + Stail) = s2; } while (0)

#define QPF(c) do {                                                     \
    _Pragma("unroll")                                                   \
    for (int j = 0; j < DCH; ++j) qn[j] = qp[((c) * DCH + j) * HW]; } while (0)

#define QMOV() do {                                                     \
    _Pragma("unroll")                                                   \
    for (int j = 0; j < DCH; ++j) qd[j] = qn[j]; } while (0)

#define COMPUTE1(Bf) do {                                               \
    const float* Bf_ = (Bf);                                            \
    _Pragma("unroll")                                                   \
    for (int j = 0; j < DCH; ++j) {                                     \
        const float* Ls = Bf_ + j * SLICE;                              \
        const float qj = qd[j];                                         \
        _Pragma("unroll")                                               \
        for (int ii = 0; ii < KSQ; ++ii)                                \
            sc[ii] = fmaf(qj, Ls[off9[ii]], sc[ii]);                    \
    } } while (0)

#define COMPUTE2(Bf, p) do {                                            \
    const float* Bf_ = (Bf);                                            \
    float o[DCH];                                                       \
    _Pragma("unroll")                                                   \
    for (int j = 0; j < DCH; ++j) {                                     \
        const float* Ls = Bf_ + j * SLICE;                              \
        float acc = 0.f;                                                \
        _Pragma("unroll")                                               \
        for (int ii = 0; ii < KSQ; ++ii)                                \
            acc = fmaf(sc[ii], Ls[off9[ii]], acc);                      \
        o[j] = acc;                                                     \
    }                                                                   \
    if (act) {                                                          \
        *(float4*)(op + (p) * DCH)     = make_float4(o[0], o[1], o[2], o[3]); \
        *(float4*)(op + (p) * DCH + 4) = make_float4(o[4], o[5], o[6], o[7]); \
    } } while (0)

__global__ __launch_bounds__(512, 6)
void dilate_attn_kernel(const float* __restrict__ q,
                        const float* __restrict__ k,
                        const float* __restrict__ v,
                        float* __restrict__ out) {
    __shared__ __align__(16) float lds[2][LBUF];  // 43008 B

    const int band = blockIdx.x;       // 0..6
    const int n    = blockIdx.y;       // head
    const int b    = blockIdx.z;

    const int tid  = threadIdx.x;      // 0..511
    const int lane = tid & 63;
    const int wv   = tid >> 6;         // 0..7: band row AND staging slice

    const bool act = lane < WW;        // lanes 56..63 idle in compute/store
    const int w  = act ? lane : (WW - 1);
    const int h0 = band * BAND;
    const int h  = h0 + wv;

    // staged (clamped, contiguous) row range
    const int lo = (h0 - 2 < 0) ? 0 : h0 - 2;
    const int hi = (h0 + 9 > HH - 1) ? HH - 1 : h0 + 9;
    const int Sbytes = (hi - lo + 1) * WW * 4;   // 2240 or 2688
    const int Stail  = Sbytes - 1024;

    // 9 window offsets inside an LDS d-slice (reflected rows/cols)
    int off9[KSQ];
    {
        int wc[3];
#pragma unroll
        for (int j = 0; j < 3; ++j) {
            int c = w + 2 * (j - 1);
            c = (c < 0) ? -c : ((c >= WW) ? (2 * WW - 2 - c) : c);
            wc[j] = c;
        }
#pragma unroll
        for (int i = 0; i < 3; ++i) {
            int rr = h + 2 * (i - 1);
            rr = (rr < 0) ? -rr : ((rr >= HH) ? (2 * HH - 2 - rr) : rr);
            rr -= lo;                  // LDS row index, in [0, nr)
#pragma unroll
            for (int j = 0; j < 3; ++j) off9[i * 3 + j] = rr * WW + wc[j];
        }
    }

    const int planebase = (b * CH + n * DD) * HW;     // first d-plane of head
    const float* qp = q + planebase + h * WW + w;
    const float* kstage = k + planebase + lo * WW;
    const float* vstage = v + planebase + lo * WW;
    float* op = out + ((b * HH + h) * WW + w) * CH + n * DD;

    float sc[KSQ];
#pragma unroll
    for (int ii = 0; ii < KSQ; ++ii) sc[ii] = 0.f;

    float qd[DCH], qn[DCH];
    float4 A0, A1, A2, B0, B1, B2;     // two named staging triples

    // ---- prologue: chunk0 -> A -> buf0 (publish); chunk1 -> B (in flight)
    LDG3(A0, A1, A2, kstage);
    LDG3(B0, B1, B2, kstage + DCH * HW);
#pragma unroll
    for (int j = 0; j < DCH; ++j) qd[j] = qp[j * HW];
    DSW3(lds[0], A0, A1, A2);          // waits only A-triple's loads
    LGKM0();
    BAR();

    // ---------------- pass 1: scores over 4 k-chunks ----------------
    // step 0: compute chunk0 (buf0); stage chunk2 -> A; write chunk1 -> buf1
    LDG3(A0, A1, A2, kstage + 2 * DCH * HW);
    QPF(1);
    COMPUTE1(lds[0]);
    QMOV();
    BAR();
    DSW3(lds[1], B0, B1, B2);
    LGKM0();
    BAR();

    // step 1: compute chunk1 (buf1); stage chunk3 -> B; write chunk2 -> buf0
    LDG3(B0, B1, B2, kstage + 3 * DCH * HW);
    QPF(2);
    COMPUTE1(lds[1]);
    QMOV();
    BAR();
    DSW3(lds[0], A0, A1, A2);
    LGKM0();
    BAR();

    // step 2: compute chunk2 (buf0); stage chunk4=v0 -> A; write chunk3 -> buf1
    LDG3(A0, A1, A2, vstage);
    QPF(3);
    COMPUTE1(lds[0]);
    QMOV();
    BAR();
    DSW3(lds[1], B0, B1, B2);
    LGKM0();
    BAR();

    // step 3: compute chunk3 (buf1); stage chunk5=v1 -> B; write chunk4 -> buf0
    LDG3(B0, B1, B2, vstage + DCH * HW);
    COMPUTE1(lds[1]);
    BAR();
    DSW3(lds[0], A0, A1, A2);
    LGKM0();
    BAR();

    // ---------------- softmax over the 9 positions ----------------
    {
        float m = sc[0];
#pragma unroll
        for (int ii = 1; ii < KSQ; ++ii) m = fmaxf(m, sc[ii]);
        float sum = 0.f;
#pragma unroll
        for (int ii = 0; ii < KSQ; ++ii) {
            sc[ii] = __expf((sc[ii] - m) * SCALE);
            sum += sc[ii];
        }
        const float inv = 1.f / sum;
#pragma unroll
        for (int ii = 0; ii < KSQ; ++ii) sc[ii] *= inv;
    }

    // ---------------- pass 2: output over 4 v-chunks ----------------
    // step 4 (p=0): compute v0 (buf0); stage v2 -> A; write v1 -> buf1
    LDG3(A0, A1, A2, vstage + 2 * DCH * HW);
    COMPUTE2(lds[0], 0);
    BAR();
    DSW3(lds[1], B0, B1, B2);
    LGKM0();
    BAR();

    // step 5 (p=1): compute v1 (buf1); stage v3 -> B; write v2 -> buf0
    LDG3(B0, B1, B2, vstage + 3 * DCH * HW);
    COMPUTE2(lds[1], 1);
    BAR();
    DSW3(lds[0], A0, A1, A2);
    LGKM0();
    BAR();

    // step 6 (p=2): compute v2 (buf0); write v3 -> buf1
    COMPUTE2(lds[0], 2);
    BAR();
    DSW3(lds[1], B0, B1, B2);
    LGKM0();
    BAR();

    // step 7 (p=3): compute v3 (buf1)
    COMPUTE2(lds[1], 3);
}

extern "C" void kernel_launch(void* const* d_in, const int* in_sizes, int n_in,
                              void* d_out, int out_size, void* d_ws, size_t ws_size,
                              hipStream_t stream) {
    const float* q = (const float*)d_in[0];
    const float* k = (const float*)d_in[1];
    const float* v = (const float*)d_in[2];
    float* out = (float*)d_out;

    dim3 grid(HH / BAND, NH, BB);   // 7 x 12 x 16 = 1344 blocks
    dilate_attn_kernel<<<grid, 512, 0, stream>>>(q, k, v, out);
}